// Round 12
// baseline (442.725 us; speedup 1.0000x reference)
//
#include <hip/hip_runtime.h>
#include <stdint.h>

// SequentialMLP (grouped MoE LLaMA-MLP), MI355X gfx950.
// E=64 experts x C=512 tokens, H=F=1024, f32 in/out, bf16 MFMA compute.
// R12: m201-style phase interleave (T3+T4+T5) on the R5 structure. Each K-tile
//      = 4 phases of {ds_read subtile | stage-issue -> s_barrier -> lgkmcnt(0)
//      -> 16 MFMA -> s_barrier}. Staging spread across phases (A-gloads in P0,
//      B scalar halves in P1/P2, vmcnt(0)+writeB in P3, 2-3 phases after
//      issue). B-staging 1-deep (R9's 2-deep spilled). All layouts R5-exact.

#define NUM_E 64
#define DIM_H 1024
#define DIM_F 1024
#define CAP   512
#define NTOK  32768

typedef short short8 __attribute__((ext_vector_type(8)));
typedef float f32x4 __attribute__((ext_vector_type(4)));

#define VMCNT(n)  asm volatile("s_waitcnt vmcnt(" #n ")" ::: "memory")
#define LGKMCNT0  asm volatile("s_waitcnt lgkmcnt(0)" ::: "memory")
#define SBAR      __builtin_amdgcn_s_barrier()
#define SCHED0    __builtin_amdgcn_sched_barrier(0)
#define SP1       __builtin_amdgcn_s_setprio(1)
#define SP0       __builtin_amdgcn_s_setprio(0)

__device__ __forceinline__ uint32_t cvtpk(float lo, float hi) {
  uint32_t r;
  asm("v_cvt_pk_bf16_f32 %0, %1, %2" : "=v"(r) : "v"(lo), "v"(hi));
  return r;
}
__device__ __forceinline__ unsigned short f2bf(float a) {
  uint32_t ua = __builtin_bit_cast(uint32_t, a);
  ua += 0x7FFFu + ((ua >> 16) & 1u);
  return (unsigned short)(ua >> 16);
}
__device__ __forceinline__ void gload_lds16(const void* g, void* l) {
  __builtin_amdgcn_global_load_lds((const __attribute__((address_space(1))) uint32_t*)g,
                                   (__attribute__((address_space(3))) uint32_t*)l, 16, 0, 0);
}

// ---------------- Kernel 0: x f32 -> bf16 ----------------
__global__ __launch_bounds__(256) void cvt_kernel(const float* __restrict__ x,
                                                  unsigned short* __restrict__ xbf) {
  size_t i = ((size_t)blockIdx.x * 256 + threadIdx.x) * 8;
  f32x4 a = *reinterpret_cast<const f32x4*>(x + i);
  f32x4 b = *reinterpret_cast<const f32x4*>(x + i + 4);
  int4 o = make_int4((int)cvtpk(a[0], a[1]), (int)cvtpk(a[2], a[3]),
                     (int)cvtpk(b[0], b[1]), (int)cvtpk(b[2], b[3]));
  *reinterpret_cast<int4*>(xbf + i) = o;
}

// ------ Kernel 1: h = silu(x Wg)*(x Wu).  256m x (128g+128u), BK=64 ------
// 512 thr / 8 waves (4m x 2n), wave tile 64x64 per matrix, 16x16x32 MFMA.
// Grid 1024. LDS 128KB: A dbuf 2x32KB @0; B dbuf 2x{Bg 16KB,Bu 16KB} @65536.
// K-tile = 4 phases: P0(k0,gate) P1(k0,up) P2(k1,gate) P3(k1,up).
__global__ __launch_bounds__(512, 2) void gateup_kernel_v11(
    const unsigned short* __restrict__ xbf, const float* __restrict__ wg,
    const float* __restrict__ wu, unsigned short* __restrict__ hout)
{
  __shared__ unsigned char smem[131072];
  const int t = threadIdx.x;
  int bid = blockIdx.x;
  bid = (bid & 7) * 128 + (bid >> 3);          // XCD-bijective (1024 = 8*128)
  const int e = bid >> 4, rr = bid & 15, mb = rr >> 3, nb = rr & 7;
  const int row0 = e * CAP + mb * 256;
  const int col0 = nb * 128;
  const unsigned short* Ag = xbf + (size_t)row0 * DIM_H;
  const float* Bgg = wg + (size_t)e * (DIM_H * DIM_F) + col0;
  const float* Bug = wu + (size_t)e * (DIM_H * DIM_F) + col0;

  const int lane = t & 63, wid = t >> 6;
  const int wm = wid >> 1, wn = wid & 1;       // wave tile 64m x 64n per matrix

  f32x4 accg[4][4], accu[4][4];
  #pragma unroll
  for (int i = 0; i < 4; i++)
    #pragma unroll
    for (int j = 0; j < 4; j++) {
      accg[i][j] = f32x4{0.f, 0.f, 0.f, 0.f};
      accu[i][j] = f32x4{0.f, 0.f, 0.f, 0.f};
    }

  // B staging (R5-exact, 1-deep): thread owns column bn, 16 k; coalesced scalars.
  const int bn = t & 127, bkb = (t >> 7) * 16;
  float bg[16], bu[16];

  auto loadB1 = [&](int k0) {
    #pragma unroll
    for (int i = 0; i < 8; i++) {
      bg[i] = Bgg[(size_t)(k0 + bkb + i) * DIM_F + bn];
      bu[i] = Bug[(size_t)(k0 + bkb + i) * DIM_F + bn];
    }
  };
  auto loadB2 = [&](int k0) {
    #pragma unroll
    for (int i = 8; i < 16; i++) {
      bg[i] = Bgg[(size_t)(k0 + bkb + i) * DIM_F + bn];
      bu[i] = Bug[(size_t)(k0 + bkb + i) * DIM_F + bn];
    }
  };
  auto writeB = [&](int b) {
    const int Bb = 65536 + b * 32768;
    #pragma unroll
    for (int j = 0; j < 4; j++) {
      int off = Bb + bn * 128 + (((bkb + j * 4) * 2) ^ ((bn & 7) << 4));
      *reinterpret_cast<uint2*>(&smem[off]) =
          make_uint2(cvtpk(bg[j*4+0], bg[j*4+1]), cvtpk(bg[j*4+2], bg[j*4+3]));
      *reinterpret_cast<uint2*>(&smem[off + 16384]) =
          make_uint2(cvtpk(bu[j*4+0], bu[j*4+1]), cvtpk(bu[j*4+2], bu[j*4+3]));
    }
  };
  // A tile 256x64 bf16 = 32KB via global_load_lds; linear dest, pre-swizzled src.
  auto loadA = [&](int k0, int buf) {
    #pragma unroll
    for (int j = 0; j < 4; j++) {
      int lin = (j * 512 + t) * 16;
      int r = lin >> 7;             // 128B per row
      int q = (lin >> 4) & 7;
      const void* src = (const unsigned char*)Ag + (size_t)r * 2048 + k0 * 2 + ((q ^ (r & 7)) * 16);
      gload_lds16(src, &smem[buf * 32768 + lin]);
    }
  };
  auto ldA = [&](short8 (&a)[4], int Ab, int kk) {
    #pragma unroll
    for (int mi = 0; mi < 4; mi++) {
      int r = wm * 64 + mi * 16 + (lane & 15);
      a[mi] = *reinterpret_cast<const short8*>(
          &smem[Ab + r * 128 + ((kk * 64 + (lane >> 4) * 16) ^ ((r & 7) << 4))]);
    }
  };
  auto ldB = [&](short8 (&bf)[4], int Bb, int kk, int uoff) {
    #pragma unroll
    for (int ni = 0; ni < 4; ni++) {
      int n = wn * 64 + ni * 16 + (lane & 15);
      bf[ni] = *reinterpret_cast<const short8*>(
          &smem[Bb + uoff + n * 128 + ((kk * 64 + (lane >> 4) * 16) ^ ((n & 7) << 4))]);
    }
  };
  auto mfq = [&](f32x4 (&acc)[4][4], const short8 (&a)[4], const short8 (&bf)[4]) {
    SP1;
    #pragma unroll
    for (int mi = 0; mi < 4; mi++)
      #pragma unroll
      for (int ni = 0; ni < 4; ni++)
        acc[mi][ni] = __builtin_amdgcn_mfma_f32_16x16x32_bf16(a[mi], bf[ni], acc[mi][ni], 0, 0, 0);
    SP0;
  };

  const int NT = DIM_H / 64;   // 16
  // prologue: B(0) scalars + A(0) gloads; drain B, write, drain A.
  loadB1(0); loadB2(0);
  loadA(0, 0);
  SCHED0;
  VMCNT(4); SCHED0;            // B(0)x32 done; A(0)x4 in flight
  writeB(0);
  VMCNT(0); LGKMCNT0; SCHED0;
  SBAR;

  #pragma unroll 1
  for (int kt = 0; kt < NT; kt++) {
    const int Ab = (kt & 1) * 32768;
    const int Bb = 65536 + (kt & 1) * 32768;
    const bool more = (kt + 1 < NT);
    short8 a[4], bf[4];
    // ---- P0 (k0, gate): reads 8; stage A(t+1) gloads ----
    ldA(a, Ab, 0); ldB(bf, Bb, 0, 0);
    if (more) loadA((kt + 1) * 64, (kt + 1) & 1);
    SCHED0;
    SBAR;
    LGKMCNT0; SCHED0;
    mfq(accg, a, bf);
    SBAR;
    // ---- P1 (k0, up): reads 4 (A in regs); stage B(t+1) half1 ----
    ldB(bf, Bb, 0, 16384);
    if (more) loadB1((kt + 1) * 64);
    SCHED0;
    SBAR;
    LGKMCNT0; SCHED0;
    mfq(accu, a, bf);
    SBAR;
    // ---- P2 (k1, gate): reads 8; stage B(t+1) half2 ----
    ldA(a, Ab, 1); ldB(bf, Bb, 1, 0);
    if (more) loadB2((kt + 1) * 64);
    SCHED0;
    SBAR;
    LGKMCNT0; SCHED0;
    mfq(accg, a, bf);
    SBAR;
    // ---- P3 (k1, up): reads 4; drain loads (issued 1-3 phases ago), writeB ----
    ldB(bf, Bb, 1, 16384);
    if (more) {
      VMCNT(0); SCHED0;
      writeB((kt + 1) & 1);
    }
    SCHED0;
    SBAR;
    LGKMCNT0; SCHED0;
    mfq(accu, a, bf);
    SBAR;
  }

  // epilogue: silu(g)*u -> bf16. C/D: col=lane&15, row=(lane>>4)*4+j.
  #pragma unroll
  for (int mi = 0; mi < 4; mi++)
    #pragma unroll
    for (int ni = 0; ni < 4; ni++) {
      int col = col0 + wn * 64 + ni * 16 + (lane & 15);
      int rbase = row0 + wm * 64 + mi * 16 + (lane >> 4) * 4;
      #pragma unroll
      for (int j = 0; j < 4; j++) {
        float gv = accg[mi][ni][j], uv = accu[mi][ni][j];
        float hv = (gv / (1.f + __expf(-gv))) * uv;
        hout[(size_t)(rbase + j) * DIM_F + col] = f2bf(hv);
      }
    }
}

// ---------------- Kernel 2: out = h Wd, f32 out.  256m x 128n ----------------
// 512 thr / 8 waves (4m x 2n), wave 64x64, 16x16x32 MFMA. Grid 1024.
// LDS 96KB: A dbuf 2x32KB @0; Bd dbuf 2x16KB @65536.
// K-tile = 4 phases: (kk-half x ni-half), 8 MFMA each.
__global__ __launch_bounds__(512, 2) void down_kernel_v11(
    const unsigned short* __restrict__ hin, const float* __restrict__ wd,
    float* __restrict__ out)
{
  __shared__ unsigned char smem[98304];
  const int t = threadIdx.x;
  int bid = blockIdx.x;
  bid = (bid & 7) * 128 + (bid >> 3);          // XCD-bijective (1024 = 8*128)
  const int e = bid >> 4, rr = bid & 15, mb = rr >> 3, nb = rr & 7;
  const int row0 = e * CAP + mb * 256;
  const int col0 = nb * 128;
  const unsigned short* Ag = hin + (size_t)row0 * DIM_F;
  const float* Bdg = wd + (size_t)e * (DIM_F * DIM_H) + col0;

  const int lane = t & 63, wid = t >> 6;
  const int wm = wid >> 1, wn = wid & 1;

  f32x4 acc[4][4];
  #pragma unroll
  for (int i = 0; i < 4; i++)
    #pragma unroll
    for (int j = 0; j < 4; j++) acc[i][j] = f32x4{0.f, 0.f, 0.f, 0.f};

  const int bn = t & 127, bkb = (t >> 7) * 16;
  float bs[16];

  auto loadB1 = [&](int k0) {
    #pragma unroll
    for (int i = 0; i < 8; i++)
      bs[i] = Bdg[(size_t)(k0 + bkb + i) * DIM_H + bn];
  };
  auto loadB2 = [&](int k0) {
    #pragma unroll
    for (int i = 8; i < 16; i++)
      bs[i] = Bdg[(size_t)(k0 + bkb + i) * DIM_H + bn];
  };
  auto writeB = [&](int b) {
    const int Bb = 65536 + b * 16384;
    #pragma unroll
    for (int j = 0; j < 4; j++) {
      int off = Bb + bn * 128 + (((bkb + j * 4) * 2) ^ ((bn & 7) << 4));
      *reinterpret_cast<uint2*>(&smem[off]) =
          make_uint2(cvtpk(bs[j*4+0], bs[j*4+1]), cvtpk(bs[j*4+2], bs[j*4+3]));
    }
  };
  auto loadA = [&](int k0, int buf) {
    #pragma unroll
    for (int j = 0; j < 4; j++) {
      int lin = (j * 512 + t) * 16;
      int r = lin >> 7;
      int q = (lin >> 4) & 7;
      const void* src = (const unsigned char*)Ag + (size_t)r * 2048 + k0 * 2 + ((q ^ (r & 7)) * 16);
      gload_lds16(src, &smem[buf * 32768 + lin]);
    }
  };
  auto ldA = [&](short8 (&a)[4], int Ab, int kk) {
    #pragma unroll
    for (int mi = 0; mi < 4; mi++) {
      int r = wm * 64 + mi * 16 + (lane & 15);
      a[mi] = *reinterpret_cast<const short8*>(
          &smem[Ab + r * 128 + ((kk * 64 + (lane >> 4) * 16) ^ ((r & 7) << 4))]);
    }
  };
  auto ldB2f = [&](short8 (&bf)[2], int Bb, int kk, int nh) {
    #pragma unroll
    for (int i = 0; i < 2; i++) {
      int n = wn * 64 + (nh * 2 + i) * 16 + (lane & 15);
      bf[i] = *reinterpret_cast<const short8*>(
          &smem[Bb + n * 128 + ((kk * 64 + (lane >> 4) * 16) ^ ((n & 7) << 4))]);
    }
  };
  auto mf8 = [&](const short8 (&a)[4], const short8 (&bf)[2], int nh) {
    SP1;
    #pragma unroll
    for (int mi = 0; mi < 4; mi++)
      #pragma unroll
      for (int i = 0; i < 2; i++)
        acc[mi][nh * 2 + i] =
            __builtin_amdgcn_mfma_f32_16x16x32_bf16(a[mi], bf[i], acc[mi][nh * 2 + i], 0, 0, 0);
    SP0;
  };

  const int NT = DIM_F / 64;   // 16
  loadB1(0); loadB2(0);
  loadA(0, 0);
  SCHED0;
  VMCNT(4); SCHED0;            // B(0)x16 done; A(0)x4 in flight
  writeB(0);
  VMCNT(0); LGKMCNT0; SCHED0;
  SBAR;

  #pragma unroll 1
  for (int kt = 0; kt < NT; kt++) {
    const int Ab = (kt & 1) * 32768;
    const int Bb = 65536 + (kt & 1) * 16384;
    const bool more = (kt + 1 < NT);
    short8 a[4], bf[2];
    // ---- P0 (k0, n-half0): stage A(t+1) ----
    ldA(a, Ab, 0); ldB2f(bf, Bb, 0, 0);
    if (more) loadA((kt + 1) * 64, (kt + 1) & 1);
    SCHED0;
    SBAR;
    LGKMCNT0; SCHED0;
    mf8(a, bf, 0);
    SBAR;
    // ---- P1 (k0, n-half1): stage B(t+1) half1 ----
    ldB2f(bf, Bb, 0, 1);
    if (more) loadB1((kt + 1) * 64);
    SCHED0;
    SBAR;
    LGKMCNT0; SCHED0;
    mf8(a, bf, 1);
    SBAR;
    // ---- P2 (k1, n-half0): stage B(t+1) half2 ----
    ldA(a, Ab, 1); ldB2f(bf, Bb, 1, 0);
    if (more) loadB2((kt + 1) * 64);
    SCHED0;
    SBAR;
    LGKMCNT0; SCHED0;
    mf8(a, bf, 0);
    SBAR;
    // ---- P3 (k1, n-half1): drain + writeB ----
    ldB2f(bf, Bb, 1, 1);
    if (more) {
      VMCNT(0); SCHED0;
      writeB((kt + 1) & 1);
    }
    SCHED0;
    SBAR;
    LGKMCNT0; SCHED0;
    mf8(a, bf, 1);
    SBAR;
  }

  #pragma unroll
  for (int mi = 0; mi < 4; mi++)
    #pragma unroll
    for (int ni = 0; ni < 4; ni++) {
      int col = col0 + wn * 64 + ni * 16 + (lane & 15);
      int rbase = row0 + wm * 64 + mi * 16 + (lane >> 4) * 4;
      #pragma unroll
      for (int j = 0; j < 4; j++)
        out[(size_t)(rbase + j) * DIM_H + col] = acc[mi][ni][j];
    }
}

extern "C" void kernel_launch(void* const* d_in, const int* in_sizes, int n_in,
                              void* d_out, int out_size, void* d_ws, size_t ws_size,
                              hipStream_t stream) {
  (void)in_sizes; (void)n_in; (void)out_size; (void)ws_size;
  const float* x  = (const float*)d_in[0];
  // d_in[1] = tokens_per_expert: equal-count setup (C=512 each), static dispatch.
  const float* wg = (const float*)d_in[2];
  const float* wu = (const float*)d_in[3];
  const float* wd = (const float*)d_in[4];
  unsigned short* h   = (unsigned short*)d_ws;                        // 64 MiB
  unsigned short* xbf = (unsigned short*)((char*)d_ws + (size_t)NTOK * DIM_F * 2); // 64 MiB
  float* out = (float*)d_out;

  cvt_kernel<<<dim3((NTOK * DIM_H) / (256 * 8)), dim3(256), 0, stream>>>(x, xbf);
  gateup_kernel_v11<<<dim3(1024), dim3(512), 0, stream>>>(xbf, wg, wu, h);
  down_kernel_v11<<<dim3(1024), dim3(512), 0, stream>>>(h, wd, out);
}

// Round 13
// 374.652 us; speedup vs baseline: 1.1817x; 1.1817x over previous
//
#include <hip/hip_runtime.h>
#include <stdint.h>

// SequentialMLP (grouped MoE LLaMA-MLP), MI355X gfx950.
// E=64 experts x C=512 tokens, H=F=1024, f32 in/out, bf16 MFMA compute.
// R13: occupancy lever (m97/m114): 2 blocks/CU instead of schedule tricks.
//      BM=256 kept (B-amortization 0.5 loads/MFMA), BN=64/matrix so LDS fits
//      2 blocks: gateup 80KB (A dbuf 2x32K + Bg 8K + Bu 8K), down 72KB.
//      512thr/8 waves, wave 64x32/matrix, acc 64 VGPR (gateup) - spill-safe.
//      Simple 2-barrier/tile loop; drains only loads issued a full compute
//      earlier. R5 layouts/swizzles byte-identical. Grid 2048, XCD swizzle.

#define NUM_E 64
#define DIM_H 1024
#define DIM_F 1024
#define CAP   512
#define NTOK  32768

typedef short short8 __attribute__((ext_vector_type(8)));
typedef float f32x4 __attribute__((ext_vector_type(4)));

#define VMCNT(n)  asm volatile("s_waitcnt vmcnt(" #n ")" ::: "memory")
#define LGKMCNT0  asm volatile("s_waitcnt lgkmcnt(0)" ::: "memory")
#define SBAR      __builtin_amdgcn_s_barrier()
#define SCHED0    __builtin_amdgcn_sched_barrier(0)

__device__ __forceinline__ uint32_t cvtpk(float lo, float hi) {
  uint32_t r;
  asm("v_cvt_pk_bf16_f32 %0, %1, %2" : "=v"(r) : "v"(lo), "v"(hi));
  return r;
}
__device__ __forceinline__ unsigned short f2bf(float a) {
  uint32_t ua = __builtin_bit_cast(uint32_t, a);
  ua += 0x7FFFu + ((ua >> 16) & 1u);
  return (unsigned short)(ua >> 16);
}
__device__ __forceinline__ void gload_lds16(const void* g, void* l) {
  __builtin_amdgcn_global_load_lds((const __attribute__((address_space(1))) uint32_t*)g,
                                   (__attribute__((address_space(3))) uint32_t*)l, 16, 0, 0);
}

// ---------------- Kernel 0: x f32 -> bf16 ----------------
__global__ __launch_bounds__(256) void cvt_kernel(const float* __restrict__ x,
                                                  unsigned short* __restrict__ xbf) {
  size_t i = ((size_t)blockIdx.x * 256 + threadIdx.x) * 8;
  f32x4 a = *reinterpret_cast<const f32x4*>(x + i);
  f32x4 b = *reinterpret_cast<const f32x4*>(x + i + 4);
  int4 o = make_int4((int)cvtpk(a[0], a[1]), (int)cvtpk(a[2], a[3]),
                     (int)cvtpk(b[0], b[1]), (int)cvtpk(b[2], b[3]));
  *reinterpret_cast<int4*>(xbf + i) = o;
}

// ------ Kernel 1: h = silu(x Wg)*(x Wu).  256m x (64g+64u), BK=64 ------
// 512 thr / 8 waves (4m x 2n), wave tile 64m x 32n per matrix, 16x16x32 MFMA.
// Grid 64e x 2mb x 16nb = 2048. LDS 80KB: A dbuf 2x32KB @0; Bg 8KB @65536;
// Bu 8KB @73728 (B single-buffered). 2 blocks/CU.
__global__ __launch_bounds__(512, 4) void gateup_kernel_v12(
    const unsigned short* __restrict__ xbf, const float* __restrict__ wg,
    const float* __restrict__ wu, unsigned short* __restrict__ hout)
{
  __shared__ unsigned char smem[81920];
  const int t = threadIdx.x;
  int bid = blockIdx.x;
  bid = (bid & 7) * 256 + (bid >> 3);          // XCD-bijective (2048 = 8*256)
  const int e = bid >> 5, rr = bid & 31, mb = rr >> 4, nb = rr & 15;
  const int row0 = e * CAP + mb * 256;
  const int col0 = nb * 64;
  const unsigned short* Ag = xbf + (size_t)row0 * DIM_H;
  const float* Bgg = wg + (size_t)e * (DIM_H * DIM_F) + col0;
  const float* Bug = wu + (size_t)e * (DIM_H * DIM_F) + col0;

  const int lane = t & 63, wid = t >> 6;
  const int wm = wid >> 1, wn = wid & 1;       // wave tile 64m x 32n per matrix

  f32x4 accg[4][2], accu[4][2];
  #pragma unroll
  for (int i = 0; i < 4; i++)
    #pragma unroll
    for (int j = 0; j < 2; j++) {
      accg[i][j] = f32x4{0.f, 0.f, 0.f, 0.f};
      accu[i][j] = f32x4{0.f, 0.f, 0.f, 0.f};
    }

  // B staging: thread owns column bn (0..63), 8 k-values; coalesced scalars.
  // Within a wave bkb is uniform, bn sweeps 0..63 -> 256B contiguous/instr.
  const int bn = t & 63, bkb = (t >> 6) * 8;
  float bg[8], bu[8];

  auto loadB = [&](int k0) {
    #pragma unroll
    for (int i = 0; i < 8; i++) {
      bg[i] = Bgg[(size_t)(k0 + bkb + i) * DIM_F + bn];
      bu[i] = Bug[(size_t)(k0 + bkb + i) * DIM_F + bn];
    }
  };
  auto writeB = [&]() {
    int off = 65536 + bn * 128 + ((bkb * 2) ^ ((bn & 7) << 4));
    *reinterpret_cast<int4*>(&smem[off]) =
        make_int4((int)cvtpk(bg[0], bg[1]), (int)cvtpk(bg[2], bg[3]),
                  (int)cvtpk(bg[4], bg[5]), (int)cvtpk(bg[6], bg[7]));
    *reinterpret_cast<int4*>(&smem[off + 8192]) =
        make_int4((int)cvtpk(bu[0], bu[1]), (int)cvtpk(bu[2], bu[3]),
                  (int)cvtpk(bu[4], bu[5]), (int)cvtpk(bu[6], bu[7]));
  };
  // A tile 256x64 bf16 = 32KB via global_load_lds; linear dest, pre-swizzled src.
  auto loadA = [&](int k0, int buf) {
    #pragma unroll
    for (int j = 0; j < 4; j++) {
      int lin = (j * 512 + t) * 16;
      int r = lin >> 7;             // 128B per row
      int q = (lin >> 4) & 7;
      const void* src = (const unsigned char*)Ag + (size_t)r * 2048 + k0 * 2 + ((q ^ (r & 7)) * 16);
      gload_lds16(src, &smem[buf * 32768 + lin]);
    }
  };
  auto compute = [&](int kt) {
    const int Ab = (kt & 1) * 32768;
    __builtin_amdgcn_s_setprio(1);
    #pragma unroll
    for (int kk = 0; kk < 2; kk++) {
      short8 a[4], bgf[2], buf_[2];
      #pragma unroll
      for (int mi = 0; mi < 4; mi++) {
        int r = wm * 64 + mi * 16 + (lane & 15);
        a[mi] = *reinterpret_cast<const short8*>(
            &smem[Ab + r * 128 + ((kk * 64 + (lane >> 4) * 16) ^ ((r & 7) << 4))]);
      }
      #pragma unroll
      for (int ni = 0; ni < 2; ni++) {
        int n = wn * 32 + ni * 16 + (lane & 15);
        int off = 65536 + n * 128 + ((kk * 64 + (lane >> 4) * 16) ^ ((n & 7) << 4));
        bgf[ni]  = *reinterpret_cast<const short8*>(&smem[off]);
        buf_[ni] = *reinterpret_cast<const short8*>(&smem[off + 8192]);
      }
      #pragma unroll
      for (int mi = 0; mi < 4; mi++)
        #pragma unroll
        for (int ni = 0; ni < 2; ni++) {
          accg[mi][ni] = __builtin_amdgcn_mfma_f32_16x16x32_bf16(a[mi], bgf[ni],  accg[mi][ni], 0, 0, 0);
          accu[mi][ni] = __builtin_amdgcn_mfma_f32_16x16x32_bf16(a[mi], buf_[ni], accu[mi][ni], 0, 0, 0);
        }
    }
    __builtin_amdgcn_s_setprio(0);
  };

  const int NT = DIM_H / 64;   // 16
  // prologue: B(0) regs + A(0) gloads; drain B, write, drain A.
  loadB(0);
  loadA(0, 0);
  SCHED0;
  VMCNT(4); SCHED0;            // B(0)x16 done; A(0)x4 in flight
  writeB();
  VMCNT(0); LGKMCNT0; SCHED0;
  SBAR;
  #pragma unroll 1
  for (int kt = 0; kt < NT; kt++) {
    const bool more = (kt + 1 < NT);
    if (more) {
      loadB((kt + 1) * 64);                    // 16 scalar loads
      loadA((kt + 1) * 64, (kt + 1) & 1);      // 4 gloads
      SCHED0;
    }
    compute(kt);
    if (more) {
      SBAR;                                    // all waves done reading B lds
      VMCNT(4); SCHED0;                        // B(t+1) regs ready; A(t+1) in flight
      writeB();
      VMCNT(0); LGKMCNT0; SCHED0;              // A(t+1) in LDS; B writes visible
      SBAR;
    }
  }

  // epilogue: silu(g)*u -> bf16. C/D: col=lane&15, row=(lane>>4)*4+j.
  #pragma unroll
  for (int mi = 0; mi < 4; mi++)
    #pragma unroll
    for (int ni = 0; ni < 2; ni++) {
      int col = col0 + wn * 32 + ni * 16 + (lane & 15);
      int rbase = row0 + wm * 64 + mi * 16 + (lane >> 4) * 4;
      #pragma unroll
      for (int j = 0; j < 4; j++) {
        float gv = accg[mi][ni][j], uv = accu[mi][ni][j];
        float hv = (gv / (1.f + __expf(-gv))) * uv;
        hout[(size_t)(rbase + j) * DIM_F + col] = f2bf(hv);
      }
    }
}

// ---------------- Kernel 2: out = h Wd, f32 out.  256m x 64n ----------------
// 512 thr / 8 waves (4m x 2n), wave 64x32, 16x16x32 MFMA. Grid 2048.
// LDS 72KB: A dbuf 2x32KB @0; Bd 8KB @65536 (single). 2 blocks/CU.
__global__ __launch_bounds__(512, 4) void down_kernel_v12(
    const unsigned short* __restrict__ hin, const float* __restrict__ wd,
    float* __restrict__ out)
{
  __shared__ unsigned char smem[73728];
  const int t = threadIdx.x;
  int bid = blockIdx.x;
  bid = (bid & 7) * 256 + (bid >> 3);          // XCD-bijective (2048 = 8*256)
  const int e = bid >> 5, rr = bid & 31, mb = rr >> 4, nb = rr & 15;
  const int row0 = e * CAP + mb * 256;
  const int col0 = nb * 64;
  const unsigned short* Ag = hin + (size_t)row0 * DIM_F;
  const float* Bdg = wd + (size_t)e * (DIM_F * DIM_H) + col0;

  const int lane = t & 63, wid = t >> 6;
  const int wm = wid >> 1, wn = wid & 1;

  f32x4 acc[4][2];
  #pragma unroll
  for (int i = 0; i < 4; i++)
    #pragma unroll
    for (int j = 0; j < 2; j++) acc[i][j] = f32x4{0.f, 0.f, 0.f, 0.f};

  const int bn = t & 63, bkb = (t >> 6) * 8;
  float bs[8];

  auto loadB = [&](int k0) {
    #pragma unroll
    for (int i = 0; i < 8; i++)
      bs[i] = Bdg[(size_t)(k0 + bkb + i) * DIM_H + bn];
  };
  auto writeB = [&]() {
    int off = 65536 + bn * 128 + ((bkb * 2) ^ ((bn & 7) << 4));
    *reinterpret_cast<int4*>(&smem[off]) =
        make_int4((int)cvtpk(bs[0], bs[1]), (int)cvtpk(bs[2], bs[3]),
                  (int)cvtpk(bs[4], bs[5]), (int)cvtpk(bs[6], bs[7]));
  };
  auto loadA = [&](int k0, int buf) {
    #pragma unroll
    for (int j = 0; j < 4; j++) {
      int lin = (j * 512 + t) * 16;
      int r = lin >> 7;
      int q = (lin >> 4) & 7;
      const void* src = (const unsigned char*)Ag + (size_t)r * 2048 + k0 * 2 + ((q ^ (r & 7)) * 16);
      gload_lds16(src, &smem[buf * 32768 + lin]);
    }
  };
  auto compute = [&](int kt) {
    const int Ab = (kt & 1) * 32768;
    __builtin_amdgcn_s_setprio(1);
    #pragma unroll
    for (int kk = 0; kk < 2; kk++) {
      short8 a[4], b[2];
      #pragma unroll
      for (int mi = 0; mi < 4; mi++) {
        int r = wm * 64 + mi * 16 + (lane & 15);
        a[mi] = *reinterpret_cast<const short8*>(
            &smem[Ab + r * 128 + ((kk * 64 + (lane >> 4) * 16) ^ ((r & 7) << 4))]);
      }
      #pragma unroll
      for (int ni = 0; ni < 2; ni++) {
        int n = wn * 32 + ni * 16 + (lane & 15);
        b[ni] = *reinterpret_cast<const short8*>(
            &smem[65536 + n * 128 + ((kk * 64 + (lane >> 4) * 16) ^ ((n & 7) << 4))]);
      }
      #pragma unroll
      for (int mi = 0; mi < 4; mi++)
        #pragma unroll
        for (int ni = 0; ni < 2; ni++)
          acc[mi][ni] = __builtin_amdgcn_mfma_f32_16x16x32_bf16(a[mi], b[ni], acc[mi][ni], 0, 0, 0);
    }
    __builtin_amdgcn_s_setprio(0);
  };

  const int NT = DIM_F / 64;   // 16
  loadB(0);
  loadA(0, 0);
  SCHED0;
  VMCNT(4); SCHED0;            // B(0)x8 done; A(0)x4 in flight
  writeB();
  VMCNT(0); LGKMCNT0; SCHED0;
  SBAR;
  #pragma unroll 1
  for (int kt = 0; kt < NT; kt++) {
    const bool more = (kt + 1 < NT);
    if (more) {
      loadB((kt + 1) * 64);
      loadA((kt + 1) * 64, (kt + 1) & 1);
      SCHED0;
    }
    compute(kt);
    if (more) {
      SBAR;
      VMCNT(4); SCHED0;
      writeB();
      VMCNT(0); LGKMCNT0; SCHED0;
      SBAR;
    }
  }

  #pragma unroll
  for (int mi = 0; mi < 4; mi++)
    #pragma unroll
    for (int ni = 0; ni < 2; ni++) {
      int col = col0 + wn * 32 + ni * 16 + (lane & 15);
      int rbase = row0 + wm * 64 + mi * 16 + (lane >> 4) * 4;
      #pragma unroll
      for (int j = 0; j < 4; j++)
        out[(size_t)(rbase + j) * DIM_H + col] = acc[mi][ni][j];
    }
}

extern "C" void kernel_launch(void* const* d_in, const int* in_sizes, int n_in,
                              void* d_out, int out_size, void* d_ws, size_t ws_size,
                              hipStream_t stream) {
  (void)in_sizes; (void)n_in; (void)out_size; (void)ws_size;
  const float* x  = (const float*)d_in[0];
  // d_in[1] = tokens_per_expert: equal-count setup (C=512 each), static dispatch.
  const float* wg = (const float*)d_in[2];
  const float* wu = (const float*)d_in[3];
  const float* wd = (const float*)d_in[4];
  unsigned short* h   = (unsigned short*)d_ws;                        // 64 MiB
  unsigned short* xbf = (unsigned short*)((char*)d_ws + (size_t)NTOK * DIM_F * 2); // 64 MiB
  float* out = (float*)d_out;

  cvt_kernel<<<dim3((NTOK * DIM_H) / (256 * 8)), dim3(256), 0, stream>>>(x, xbf);
  gateup_kernel_v12<<<dim3(2048), dim3(512), 0, stream>>>(xbf, wg, wu, h);
  down_kernel_v12<<<dim3(2048), dim3(512), 0, stream>>>(h, wd, out);
}